// Round 3
// baseline (205.488 us; speedup 1.0000x reference)
//
#include <hip/hip_runtime.h>
#include <stdint.h>

typedef __bf16 bf16_t;
typedef bf16_t bf16x8 __attribute__((ext_vector_type(8)));
typedef float f32x4 __attribute__((ext_vector_type(4)));
typedef unsigned short us8 __attribute__((ext_vector_type(8)));
typedef unsigned short us4 __attribute__((ext_vector_type(4)));
typedef unsigned int u32x4 __attribute__((ext_vector_type(4)));

#define B_ 4
#define T_ 4096
#define C_ 1024
#define D_ 128

#define NCHUNK_PB 144   // per batch: sum over 32 q-tiles(128) of ceil((2jt+2)/8)
#define QSCALE 0.12751744f  // (1/sqrt(128)) * log2(e), folded into Q
#define M0 14.0f            // fixed softmax base (log2 domain); cancels in combine

__device__ __forceinline__ uint16_t f2bf(float f) {
    union { float f; uint32_t u; } v; v.f = f;
    uint32_t u = v.u;
    uint32_t r = (u + 0x7fffu + ((u >> 16) & 1u)) >> 16;
    return (uint16_t)r;
}

// round-half-up bf16 (2 VALU)
__device__ __forceinline__ uint16_t bfru(float f) {
    return (uint16_t)((__float_as_uint(f) + 0x8000u) >> 16);
}

__device__ __forceinline__ float bf2f(uint16_t u) {
    return __uint_as_float((uint32_t)u << 16);
}

// async global->LDS DMA, 16 B per lane. LDS dest = wave-uniform base + lane*16.
__device__ __forceinline__ void gload_lds16(const void* g, void* l) {
    __builtin_amdgcn_global_load_lds(
        (const __attribute__((address_space(1))) void*)g,
        (__attribute__((address_space(3))) void*)l, 16, 0, 0);
}

// ---------------------------------------------------------------------------
// Kernel 1: W[C,D] fp32 -> WT[w][n][k] bf16 (transposed), w in {q,k,v}
// ---------------------------------------------------------------------------
__global__ __launch_bounds__(256) void prep_w(const float* __restrict__ Wq,
                                              const float* __restrict__ Wk,
                                              const float* __restrict__ Wv,
                                              uint16_t* __restrict__ WT) {
    int idx = blockIdx.x * 256 + threadIdx.x;
    if (idx >= 3 * D_ * C_) return;
    int w   = idx / (D_ * C_);
    int rem = idx - w * (D_ * C_);
    int n   = rem / C_;
    int k   = rem - n * C_;
    const float* W = (w == 0) ? Wq : (w == 1) ? Wk : Wv;
    WT[idx] = f2bf(W[(size_t)k * D_ + n]);
}

// ---------------------------------------------------------------------------
// Kernel 2: QKV projection (R4 structure). grid = 3 W x 256 M-tiles(64 rows).
// BK=64. Q gets QSCALE folded in.
// ---------------------------------------------------------------------------
#define GST 72   // 64+8 elems leading-dim pad

__global__ __launch_bounds__(256) void qkv_gemm(const float* __restrict__ x,
                                                const uint16_t* __restrict__ WT,
                                                uint16_t* __restrict__ qb,
                                                uint16_t* __restrict__ kb,
                                                uint16_t* __restrict__ vT) {
    __shared__ __align__(16) uint16_t A_lds[64 * GST];
    __shared__ __align__(16) uint16_t W_lds[128 * GST];

    int tid  = threadIdx.x;
    int lane = tid & 63;
    int wave = tid >> 6;
    int quad = lane >> 4;
    int lx   = lane & 15;
    int wm   = wave >> 1, wn = wave & 1;

    int bx   = blockIdx.x;
    int wsel = bx % 3;
    int m0   = (bx / 3) * 64;
    const uint16_t* Wp = WT + (size_t)wsel * (D_ * C_);

    f32x4 acc[2][4];
    for (int mf = 0; mf < 2; mf++)
        for (int nf = 0; nf < 4; nf++)
            acc[mf][nf] = (f32x4){0.f, 0.f, 0.f, 0.f};

    int arow = tid >> 2, acb = (tid & 3) * 16;  // A: 16 floats/thread
    int wrow = tid >> 1, wcb = (tid & 1) * 32;  // W: 32 bf16/thread

    for (int k0 = 0; k0 < C_; k0 += 64) {
        // stage A (fp32 -> bf16 packed via v_perm)
        {
            const float* xp = x + (size_t)(m0 + arow) * C_ + k0 + acb;
            uint32_t d[8];
#pragma unroll
            for (int j = 0; j < 4; j++) {
                float4 f = *(const float4*)(xp + j * 4);
                uint32_t u0 = __float_as_uint(f.x) + 0x8000u;
                uint32_t u1 = __float_as_uint(f.y) + 0x8000u;
                uint32_t u2 = __float_as_uint(f.z) + 0x8000u;
                uint32_t u3 = __float_as_uint(f.w) + 0x8000u;
                d[2 * j]     = __builtin_amdgcn_perm(u1, u0, 0x07060302);
                d[2 * j + 1] = __builtin_amdgcn_perm(u3, u2, 0x07060302);
            }
            *(u32x4*)&A_lds[arow * GST + acb]     = (u32x4){d[0], d[1], d[2], d[3]};
            *(u32x4*)&A_lds[arow * GST + acb + 8] = (u32x4){d[4], d[5], d[6], d[7]};
        }
        // stage W slice (bf16, transposed already)
        {
            const uint16_t* wp = Wp + (size_t)wrow * C_ + k0 + wcb;
#pragma unroll
            for (int i = 0; i < 4; i++)
                *(us8*)&W_lds[wrow * GST + wcb + i * 8] = *(const us8*)(wp + i * 8);
        }
        __syncthreads();

#pragma unroll
        for (int kc = 0; kc < 2; kc++) {
            bf16x8 af[2];
#pragma unroll
            for (int mf = 0; mf < 2; mf++)
                af[mf] = *(const bf16x8*)&A_lds[(wm * 32 + mf * 16 + lx) * GST + kc * 32 + quad * 8];
#pragma unroll
            for (int nf = 0; nf < 4; nf++) {
                bf16x8 bf = *(const bf16x8*)&W_lds[(wn * 64 + nf * 16 + lx) * GST + kc * 32 + quad * 8];
                acc[0][nf] = __builtin_amdgcn_mfma_f32_16x16x32_bf16(af[0], bf, acc[0][nf], 0, 0, 0);
                acc[1][nf] = __builtin_amdgcn_mfma_f32_16x16x32_bf16(af[1], bf, acc[1][nf], 0, 0, 0);
            }
        }
        __syncthreads();
    }

    // epilogue: C-layout row = quad*4+r, col = lx
    int mrow0 = m0 + wm * 32 + quad * 4;
    if (wsel == 2) {
#pragma unroll
        for (int mf = 0; mf < 2; mf++) {
            int mbase = mrow0 + mf * 16;
            int batch = mbase >> 12;
            int t     = mbase & 4095;
#pragma unroll
            for (int nf = 0; nf < 4; nf++) {
                int n = wn * 64 + nf * 16 + lx;
                us4 pv;
#pragma unroll
                for (int r = 0; r < 4; r++) pv[r] = bfru(acc[mf][nf][r]);
                *(us4*)&vT[(size_t)batch * D_ * T_ + (size_t)n * T_ + t] = pv;
            }
        }
    } else {
        uint16_t* dst = (wsel == 0) ? qb : kb;
        float sc = (wsel == 0) ? QSCALE : 1.0f;
#pragma unroll
        for (int mf = 0; mf < 2; mf++)
#pragma unroll
            for (int nf = 0; nf < 4; nf++) {
                int n = wn * 64 + nf * 16 + lx;
#pragma unroll
                for (int r = 0; r < 4; r++)
                    dst[(size_t)(mrow0 + mf * 16 + r) * D_ + n] = bfru(acc[mf][nf][r] * sc);
            }
    }
}

// ---------------------------------------------------------------------------
// Kernel 3: split-K flash attention, fixed-base softmax (no online max).
// R7: Q-tile = 128 rows (wave owns 32 q-rows, 2 m-frags). Each staged K/V
// tile now feeds 128 q-rows instead of 64 -> total tile-iters halve
// (8320 -> 4224), halving LDS-pipe read traffic (the measured bottleneck:
// ~34us of LDS time at 70us wall), DMA writes, and L2 traffic. MFMA/VALU
// totals unchanged. LDS = 80KB exactly -> still 2 blocks/CU. DMA double-
// buffered staging kept from R6 (clean traffic, VGPR-free).
// ---------------------------------------------------------------------------
__global__ __launch_bounds__(256, 2) void attn(const uint16_t* __restrict__ qb,
                                               const uint16_t* __restrict__ kb,
                                               const uint16_t* __restrict__ vT,
                                               uint16_t* __restrict__ part,
                                               float* __restrict__ ml) {
    __shared__ __align__(16) uint16_t K_lds[2][64 * 128];    // 2 x 16384 B
    __shared__ __align__(16) uint16_t V_lds[2][128 * 64];    // 2 x 16384 B
    __shared__ __align__(16) uint16_t P_lds[4 * 32 * 64];    //    16384 B

    int tid  = threadIdx.x;
    int lane = tid & 63;
    int wave = tid >> 6;
    int quad = lane >> 4;
    int lx   = lane & 15;
    int lx7  = lx & 7;

    // decode blockIdx -> (batch, logical chunk L), longest chunks first.
    // q-tile jt in [0,32): 2jt+2 key-tiles, nc(jt)=jt/4+1 chunks.
    // cumulative chunks before group a (jt<4a): 2a(a+1).
    int batch = blockIdx.x & 3;
    int L     = NCHUNK_PB - 1 - (blockIdx.x >> 2);
    int a = 0;
    while (a < 7 && 2 * (a + 1) * (a + 2) <= L) a++;
    int rem   = L - 2 * a * (a + 1);
    int jt    = 4 * a + rem / (a + 1);
    int chunk = rem - (rem / (a + 1)) * (a + 1);
    int lidx  = batch * NCHUNK_PB + L;

    int q0     = jt * 128;
    int st0    = chunk * 8;
    int ntiles = min(8, 2 * jt + 2 - st0);

    // issue one K+V tile into buffer bi via DMA (unchanged from R6).
    auto issue_kv = [&](int bi, int tile) {
        int s0i = tile * 64;
        const uint16_t* kB = kb + (size_t)(batch * T_ + s0i) * D_;
#pragma unroll
        for (int j = 0; j < 4; j++) {
            int row = wave * 16 + j * 4 + (lane >> 4);
            int gch = (lane & 15) ^ (row & 7);
            gload_lds16(kB + (size_t)row * D_ + gch * 8,
                        &K_lds[bi][(wave * 16 + j * 4) * 128]);
        }
        const uint16_t* vB = vT + (size_t)batch * D_ * T_ + s0i;
#pragma unroll
        for (int j = 0; j < 4; j++) {
            int row = wave * 32 + j * 8 + (lane >> 3);
            int gch = (lane & 7) ^ (row & 7);
            gload_lds16(vB + (size_t)row * T_ + gch * 8,
                        &V_lds[bi][(wave * 32 + j * 8) * 64]);
        }
    };

    bf16x8 qf[2][4];
#pragma unroll
    for (int mf = 0; mf < 2; mf++) {
        const uint16_t* qp = qb + (size_t)(batch * T_ + q0 + wave * 32 + mf * 16 + lx) * D_ + quad * 8;
#pragma unroll
        for (int kc = 0; kc < 4; kc++) qf[mf][kc] = *(const bf16x8*)(qp + kc * 32);
    }

    f32x4 o[2][8];
#pragma unroll
    for (int mf = 0; mf < 2; mf++)
#pragma unroll
        for (int i = 0; i < 8; i++) o[mf][i] = (f32x4){0.f, 0.f, 0.f, 0.f};
    float l_i[2][4] = {{0.f, 0.f, 0.f, 0.f}, {0.f, 0.f, 0.f, 0.f}};

    issue_kv(0, st0);   // prologue prefetch
    int cur = 0;

    for (int it = 0; it < ntiles; it++) {
        int s0 = (st0 + it) * 64;
        // drains this wave's DMA (vmcnt(0) implicit) -> buf[cur] ready;
        // also guarantees all waves finished reading buf[cur^1] last iter.
        __syncthreads();
        if (it + 1 < ntiles) issue_kv(cur ^ 1, st0 + it + 1);

        // S = Q K^T (pre-scaled by QSCALE, log2 domain); K frags reused 2x
        f32x4 s[2][4];
#pragma unroll
        for (int mf = 0; mf < 2; mf++)
#pragma unroll
            for (int nf = 0; nf < 4; nf++) s[mf][nf] = (f32x4){0.f, 0.f, 0.f, 0.f};
        __builtin_amdgcn_s_setprio(1);
#pragma unroll
        for (int kc = 0; kc < 4; kc++)
#pragma unroll
            for (int nf = 0; nf < 4; nf++) {
                bf16x8 kf = *(const bf16x8*)&K_lds[cur][(nf * 16 + lx) * 128 + (((kc * 4 + quad) ^ lx7) * 8)];
                s[0][nf] = __builtin_amdgcn_mfma_f32_16x16x32_bf16(qf[0][kc], kf, s[0][nf], 0, 0, 0);
                s[1][nf] = __builtin_amdgcn_mfma_f32_16x16x32_bf16(qf[1][kc], kf, s[1][nf], 0, 0, 0);
            }
        __builtin_amdgcn_s_setprio(0);

        float p[2][4][4];
#pragma unroll
        for (int mf = 0; mf < 2; mf++)
#pragma unroll
            for (int nf = 0; nf < 4; nf++)
#pragma unroll
                for (int r = 0; r < 4; r++) p[mf][nf][r] = s[mf][nf][r];

        // causal mask on the two diagonal tiles (wave-uniform branch)
        if (st0 + it >= 2 * jt) {
#pragma unroll
            for (int mf = 0; mf < 2; mf++) {
                int rowg = q0 + wave * 32 + mf * 16 + quad * 4;
#pragma unroll
                for (int nf = 0; nf < 4; nf++) {
                    int colg = s0 + nf * 16 + lx;
#pragma unroll
                    for (int r = 0; r < 4; r++)
                        if (colg > rowg + r) p[mf][nf][r] = -INFINITY;
                }
            }
        }

        // p = exp2(s - M0); accumulate denominator per-lane (no reductions)
#pragma unroll
        for (int mf = 0; mf < 2; mf++) {
#pragma unroll
            for (int nf = 0; nf < 4; nf++)
#pragma unroll
                for (int r = 0; r < 4; r++)
                    p[mf][nf][r] = exp2f(p[mf][nf][r] - M0);
#pragma unroll
            for (int r = 0; r < 4; r++)
                l_i[mf][r] += (p[mf][0][r] + p[mf][1][r]) + (p[mf][2][r] + p[mf][3][r]);
        }

        // P (C-layout) -> LDS, pair-packed b32 writes from even lanes, swizzled
        // (per-wave region; same-wave RAW ordered by lgkmcnt, no barrier needed)
#pragma unroll
        for (int mf = 0; mf < 2; mf++)
#pragma unroll
            for (int nf = 0; nf < 4; nf++)
#pragma unroll
                for (int r = 0; r < 4; r++) {
                    uint32_t u  = __float_as_uint(p[mf][nf][r]) + 0x8000u;
                    uint32_t pu = (uint32_t)__shfl_xor((int)u, 1, 64);
                    uint32_t pk = __builtin_amdgcn_perm(pu, u, 0x07060302);
                    if ((lane & 1) == 0) {
                        int prow = mf * 16 + quad * 4 + r;
                        int pchk = nf * 2 + (lx >> 3);
                        *(uint32_t*)&P_lds[wave * 2048 + prow * 64 + ((pchk ^ (prow & 7)) * 8) + lx7] = pk;
                    }
                }

        bf16x8 pf[2][2];
#pragma unroll
        for (int mf = 0; mf < 2; mf++) {
            pf[mf][0] = *(const bf16x8*)&P_lds[wave * 2048 + (mf * 16 + lx) * 64 + ((quad ^ lx7) * 8)];
            pf[mf][1] = *(const bf16x8*)&P_lds[wave * 2048 + (mf * 16 + lx) * 64 + (((4 + quad) ^ lx7) * 8)];
        }
        __builtin_amdgcn_s_setprio(1);
#pragma unroll
        for (int nf = 0; nf < 8; nf++)
#pragma unroll
            for (int kc = 0; kc < 2; kc++) {
                bf16x8 vf = *(const bf16x8*)&V_lds[cur][(nf * 16 + lx) * 64 + (((kc * 4 + quad) ^ lx7) * 8)];
                o[0][nf] = __builtin_amdgcn_mfma_f32_16x16x32_bf16(pf[0][kc], vf, o[0][nf], 0, 0, 0);
                o[1][nf] = __builtin_amdgcn_mfma_f32_16x16x32_bf16(pf[1][kc], vf, o[1][nf], 0, 0, 0);
            }
        __builtin_amdgcn_s_setprio(0);
        cur ^= 1;
    }

    // reduce l across the 16 lanes of each quarter-row group (once per kernel)
#pragma unroll
    for (int off = 1; off < 16; off <<= 1)
#pragma unroll
        for (int mf = 0; mf < 2; mf++)
#pragma unroll
            for (int r = 0; r < 4; r++)
                l_i[mf][r] += __shfl_xor(l_i[mf][r], off, 64);

    // write unnormalized partial (bf16) + l at the LOGICAL index
    uint16_t* pp = part + (size_t)lidx * (128 * 128);
#pragma unroll
    for (int mf = 0; mf < 2; mf++)
#pragma unroll
        for (int nf = 0; nf < 8; nf++)
#pragma unroll
            for (int r = 0; r < 4; r++) {
                int lrow = wave * 32 + mf * 16 + quad * 4 + r;
                pp[lrow * 128 + nf * 16 + lx] = bfru(o[mf][nf][r]);
            }
    if (lx == 0) {
#pragma unroll
        for (int mf = 0; mf < 2; mf++)
#pragma unroll
            for (int r = 0; r < 4; r++)
                ml[(size_t)lidx * 128 + wave * 32 + mf * 16 + quad * 4 + r] = l_i[mf][r];
    }
}

// ---------------------------------------------------------------------------
// Kernel 4: combine split-K partials: plain sums (fixed M0 cancels).
// Grid = (batch, jt128, col-half): 256 blocks; thread = (row, col-quarter).
// ---------------------------------------------------------------------------
__global__ __launch_bounds__(256) void combine(const uint16_t* __restrict__ part,
                                               const float* __restrict__ ml,
                                               float* __restrict__ out) {
    int bidx  = blockIdx.x;
    int half  = bidx & 1;
    int jt    = (bidx >> 1) & 31;
    int batch = bidx >> 6;
    int a     = jt >> 2;
    int base  = batch * NCHUNK_PB + 2 * a * (a + 1) + (jt - 4 * a) * (a + 1);
    int nch   = a + 1;

    int tid  = threadIdx.x;
    int lrow = tid >> 1;                 // 0..127
    int c0   = half * 64 + (tid & 1) * 32;

    float Lsum = 0.f;
    f32x4 acc[8];
#pragma unroll
    for (int i = 0; i < 8; i++) acc[i] = (f32x4){0.f, 0.f, 0.f, 0.f};

    for (int c = 0; c < nch; c++) {
        Lsum += ml[(size_t)(base + c) * 128 + lrow];
        const uint16_t* p = part + (size_t)(base + c) * (128 * 128) + lrow * 128 + c0;
#pragma unroll
        for (int i = 0; i < 4; i++) {
            us8 v = *(const us8*)(p + i * 8);
#pragma unroll
            for (int j = 0; j < 8; j++)
                acc[i * 2 + (j >> 2)][j & 3] += bf2f(v[j]);
        }
    }
    float inv = 1.f / Lsum;
    size_t row = (size_t)(batch * T_ + jt * 128 + lrow);
#pragma unroll
    for (int i = 0; i < 8; i++)
        *(f32x4*)(out + row * 128 + c0 + i * 4) = acc[i] * inv;
}

// ---------------------------------------------------------------------------
extern "C" void kernel_launch(void* const* d_in, const int* in_sizes, int n_in,
                              void* d_out, int out_size, void* d_ws, size_t ws_size,
                              hipStream_t stream) {
    const float* x  = (const float*)d_in[0];
    const float* Wq = (const float*)d_in[1];
    const float* Wk = (const float*)d_in[2];
    const float* Wv = (const float*)d_in[3];
    float* out = (float*)d_out;

    uint16_t* ws = (uint16_t*)d_ws;
    uint16_t* qb = ws;                                   // 16384*128 bf16
    uint16_t* kb = qb + (size_t)16384 * 128;
    uint16_t* vT = kb + (size_t)16384 * 128;
    uint16_t* WT = vT + (size_t)16384 * 128;             // 3*128*1024
    uint16_t* part = WT + (size_t)3 * D_ * C_;           // 576*128*128 bf16
    float* ml = (float*)(part + (size_t)4 * NCHUNK_PB * 128 * 128);  // 576*128 fp32

    prep_w<<<dim3((3 * D_ * C_ + 255) / 256), dim3(256), 0, stream>>>(Wq, Wk, Wv, WT);
    qkv_gemm<<<dim3(3 * (16384 / 64)), dim3(256), 0, stream>>>(x, WT, qb, kb, vT);
    attn<<<dim3(B_ * NCHUNK_PB), dim3(256), 0, stream>>>(qb, kb, vT, part, ml);
    combine<<<dim3(B_ * 32 * 2), dim3(256), 0, stream>>>(part, ml, out);
}

// Round 4
// 185.554 us; speedup vs baseline: 1.1074x; 1.1074x over previous
//
#include <hip/hip_runtime.h>
#include <stdint.h>

typedef __bf16 bf16_t;
typedef bf16_t bf16x8 __attribute__((ext_vector_type(8)));
typedef float f32x4 __attribute__((ext_vector_type(4)));
typedef float f32x16 __attribute__((ext_vector_type(16)));
typedef unsigned short us8 __attribute__((ext_vector_type(8)));
typedef unsigned short us4 __attribute__((ext_vector_type(4)));
typedef unsigned int u32x4 __attribute__((ext_vector_type(4)));

#define B_ 4
#define T_ 4096
#define C_ 1024
#define D_ 128

#define NCHUNK_PB 144   // per batch: sum over 32 q-tiles(128) of ceil((2jt+2)/8)
#define QSCALE 0.12751744f  // (1/sqrt(128)) * log2(e), folded into Q
#define M0 14.0f            // fixed softmax base (log2 domain); cancels in combine

__device__ __forceinline__ uint16_t f2bf(float f) {
    union { float f; uint32_t u; } v; v.f = f;
    uint32_t u = v.u;
    uint32_t r = (u + 0x7fffu + ((u >> 16) & 1u)) >> 16;
    return (uint16_t)r;
}

// round-half-up bf16 (2 VALU)
__device__ __forceinline__ uint16_t bfru(float f) {
    return (uint16_t)((__float_as_uint(f) + 0x8000u) >> 16);
}

__device__ __forceinline__ float bf2f(uint16_t u) {
    return __uint_as_float((uint32_t)u << 16);
}

// pack 2 f32 -> u32 of 2 bf16 (lo=a, hi=b); no builtin on gfx950 (T12 recipe)
__device__ __forceinline__ uint32_t cvtpk(float a, float b) {
    uint32_t r;
    asm("v_cvt_pk_bf16_f32 %0, %1, %2" : "=v"(r) : "v"(a), "v"(b));
    return r;
}

// v_permlane32_swap_b32: exchanges a.lanes[32:63] <-> b.lanes[0:31].
// After: a = [a.lo | b.lo], b = [a.hi | b.hi] (q index = lane&31 preserved).
__device__ __forceinline__ void pl32swap(uint32_t& a, uint32_t& b) {
    asm("v_permlane32_swap_b32 %0, %1" : "+v"(a), "+v"(b));
}

// async global->LDS DMA, 16 B per lane. LDS dest = wave-uniform base + lane*16.
__device__ __forceinline__ void gload_lds16(const void* g, void* l) {
    __builtin_amdgcn_global_load_lds(
        (const __attribute__((address_space(1))) void*)g,
        (__attribute__((address_space(3))) void*)l, 16, 0, 0);
}

// ---------------------------------------------------------------------------
// Kernel 1: W[C,D] fp32 -> WT[w][n][k] bf16 (transposed), w in {q,k,v}
// ---------------------------------------------------------------------------
__global__ __launch_bounds__(256) void prep_w(const float* __restrict__ Wq,
                                              const float* __restrict__ Wk,
                                              const float* __restrict__ Wv,
                                              uint16_t* __restrict__ WT) {
    int idx = blockIdx.x * 256 + threadIdx.x;
    if (idx >= 3 * D_ * C_) return;
    int w   = idx / (D_ * C_);
    int rem = idx - w * (D_ * C_);
    int n   = rem / C_;
    int k   = rem - n * C_;
    const float* W = (w == 0) ? Wq : (w == 1) ? Wk : Wv;
    WT[idx] = f2bf(W[(size_t)k * D_ + n]);
}

// ---------------------------------------------------------------------------
// Kernel 2: QKV projection (R4 structure). grid = 3 W x 256 M-tiles(64 rows).
// BK=64. Q gets QSCALE folded in.
// ---------------------------------------------------------------------------
#define GST 72   // 64+8 elems leading-dim pad

__global__ __launch_bounds__(256) void qkv_gemm(const float* __restrict__ x,
                                                const uint16_t* __restrict__ WT,
                                                uint16_t* __restrict__ qb,
                                                uint16_t* __restrict__ kb,
                                                uint16_t* __restrict__ vT) {
    __shared__ __align__(16) uint16_t A_lds[64 * GST];
    __shared__ __align__(16) uint16_t W_lds[128 * GST];

    int tid  = threadIdx.x;
    int lane = tid & 63;
    int wave = tid >> 6;
    int quad = lane >> 4;
    int lx   = lane & 15;
    int wm   = wave >> 1, wn = wave & 1;

    int bx   = blockIdx.x;
    int wsel = bx % 3;
    int m0   = (bx / 3) * 64;
    const uint16_t* Wp = WT + (size_t)wsel * (D_ * C_);

    f32x4 acc[2][4];
    for (int mf = 0; mf < 2; mf++)
        for (int nf = 0; nf < 4; nf++)
            acc[mf][nf] = (f32x4){0.f, 0.f, 0.f, 0.f};

    int arow = tid >> 2, acb = (tid & 3) * 16;  // A: 16 floats/thread
    int wrow = tid >> 1, wcb = (tid & 1) * 32;  // W: 32 bf16/thread

    for (int k0 = 0; k0 < C_; k0 += 64) {
        // stage A (fp32 -> bf16 packed via v_perm)
        {
            const float* xp = x + (size_t)(m0 + arow) * C_ + k0 + acb;
            uint32_t d[8];
#pragma unroll
            for (int j = 0; j < 4; j++) {
                float4 f = *(const float4*)(xp + j * 4);
                uint32_t u0 = __float_as_uint(f.x) + 0x8000u;
                uint32_t u1 = __float_as_uint(f.y) + 0x8000u;
                uint32_t u2 = __float_as_uint(f.z) + 0x8000u;
                uint32_t u3 = __float_as_uint(f.w) + 0x8000u;
                d[2 * j]     = __builtin_amdgcn_perm(u1, u0, 0x07060302);
                d[2 * j + 1] = __builtin_amdgcn_perm(u3, u2, 0x07060302);
            }
            *(u32x4*)&A_lds[arow * GST + acb]     = (u32x4){d[0], d[1], d[2], d[3]};
            *(u32x4*)&A_lds[arow * GST + acb + 8] = (u32x4){d[4], d[5], d[6], d[7]};
        }
        // stage W slice (bf16, transposed already)
        {
            const uint16_t* wp = Wp + (size_t)wrow * C_ + k0 + wcb;
#pragma unroll
            for (int i = 0; i < 4; i++)
                *(us8*)&W_lds[wrow * GST + wcb + i * 8] = *(const us8*)(wp + i * 8);
        }
        __syncthreads();

#pragma unroll
        for (int kc = 0; kc < 2; kc++) {
            bf16x8 af[2];
#pragma unroll
            for (int mf = 0; mf < 2; mf++)
                af[mf] = *(const bf16x8*)&A_lds[(wm * 32 + mf * 16 + lx) * GST + kc * 32 + quad * 8];
#pragma unroll
            for (int nf = 0; nf < 4; nf++) {
                bf16x8 bf = *(const bf16x8*)&W_lds[(wn * 64 + nf * 16 + lx) * GST + kc * 32 + quad * 8];
                acc[0][nf] = __builtin_amdgcn_mfma_f32_16x16x32_bf16(af[0], bf, acc[0][nf], 0, 0, 0);
                acc[1][nf] = __builtin_amdgcn_mfma_f32_16x16x32_bf16(af[1], bf, acc[1][nf], 0, 0, 0);
            }
        }
        __syncthreads();
    }

    // epilogue: C-layout row = quad*4+r, col = lx
    int mrow0 = m0 + wm * 32 + quad * 4;
    if (wsel == 2) {
#pragma unroll
        for (int mf = 0; mf < 2; mf++) {
            int mbase = mrow0 + mf * 16;
            int batch = mbase >> 12;
            int t     = mbase & 4095;
#pragma unroll
            for (int nf = 0; nf < 4; nf++) {
                int n = wn * 64 + nf * 16 + lx;
                us4 pv;
#pragma unroll
                for (int r = 0; r < 4; r++) pv[r] = bfru(acc[mf][nf][r]);
                *(us4*)&vT[(size_t)batch * D_ * T_ + (size_t)n * T_ + t] = pv;
            }
        }
    } else {
        uint16_t* dst = (wsel == 0) ? qb : kb;
        float sc = (wsel == 0) ? QSCALE : 1.0f;
#pragma unroll
        for (int mf = 0; mf < 2; mf++)
#pragma unroll
            for (int nf = 0; nf < 4; nf++) {
                int n = wn * 64 + nf * 16 + lx;
#pragma unroll
                for (int r = 0; r < 4; r++)
                    dst[(size_t)(mrow0 + mf * 16 + r) * D_ + n] = bfru(acc[mf][nf][r] * sc);
            }
    }
}

// ---------------------------------------------------------------------------
// Kernel 3: split-K flash attention, fixed-base softmax (no online max).
// R8 (T12): swapped QK^T at 32x32x16 -> S^T in registers with q lane-local.
//   D layout: col=lane&31=q, row=(r&3)+8*(r>>2)+4*(lane>>5)=s.
//   P never touches LDS: 16 cvt_pk + 8 permlane32_swap build the PV A-frags
//   in-register. DS ops/wave/iter: 100 -> 32 (K 16 + V 16). P_lds deleted
//   (LDS 64KB, 2 blocks/CU). DMA double-buffered staging kept from R6/R7.
// ---------------------------------------------------------------------------
__global__ __launch_bounds__(256, 2) void attn(const uint16_t* __restrict__ qb,
                                               const uint16_t* __restrict__ kb,
                                               const uint16_t* __restrict__ vT,
                                               uint16_t* __restrict__ part,
                                               float* __restrict__ ml) {
    __shared__ __align__(16) uint16_t K_lds[2][64 * 128];    // 2 x 16384 B
    __shared__ __align__(16) uint16_t V_lds[2][128 * 64];    // 2 x 16384 B

    int tid  = threadIdx.x;
    int lane = tid & 63;
    int wave = tid >> 6;
    int q31  = lane & 31;   // q column (and d-row / s-row index in frags)
    int hi   = lane >> 5;   // kb group

    // decode blockIdx -> (batch, logical chunk L), longest chunks first.
    int batch = blockIdx.x & 3;
    int L     = NCHUNK_PB - 1 - (blockIdx.x >> 2);
    int a = 0;
    while (a < 7 && 2 * (a + 1) * (a + 2) <= L) a++;
    int rem   = L - 2 * a * (a + 1);
    int jt    = 4 * a + rem / (a + 1);
    int chunk = rem - (rem / (a + 1)) * (a + 1);
    int lidx  = batch * NCHUNK_PB + L;

    int q0     = jt * 128;
    int st0    = chunk * 8;
    int ntiles = min(8, 2 * jt + 2 - st0);

    // issue one K+V tile into buffer bi via DMA (unchanged from R6/R7).
    auto issue_kv = [&](int bi, int tile) {
        int s0i = tile * 64;
        const uint16_t* kB = kb + (size_t)(batch * T_ + s0i) * D_;
#pragma unroll
        for (int j = 0; j < 4; j++) {
            int row = wave * 16 + j * 4 + (lane >> 4);
            int gch = (lane & 15) ^ (row & 7);
            gload_lds16(kB + (size_t)row * D_ + gch * 8,
                        &K_lds[bi][(wave * 16 + j * 4) * 128]);
        }
        const uint16_t* vB = vT + (size_t)batch * D_ * T_ + s0i;
#pragma unroll
        for (int j = 0; j < 4; j++) {
            int row = wave * 32 + j * 8 + (lane >> 3);
            int gch = (lane & 7) ^ (row & 7);
            gload_lds16(vB + (size_t)row * T_ + gch * 8,
                        &V_lds[bi][(wave * 32 + j * 8) * 64]);
        }
    };

    // Q fragments (B operand): lane = q + 32*kb holds d = kc*16 + kb*8 + j
    bf16x8 qf[8];
    {
        const uint16_t* qp = qb + (size_t)(batch * T_ + q0 + wave * 32 + q31) * D_ + hi * 8;
#pragma unroll
        for (int kc = 0; kc < 8; kc++) qf[kc] = *(const bf16x8*)(qp + kc * 16);
    }

    f32x16 o[4];
#pragma unroll
    for (int i = 0; i < 4; i++)
#pragma unroll
        for (int r = 0; r < 16; r++) o[i][r] = 0.f;
    float lsum = 0.f;

    issue_kv(0, st0);   // prologue prefetch
    int cur = 0;

    for (int it = 0; it < ntiles; it++) {
        int s0 = (st0 + it) * 64;
        // drains this wave's DMA (vmcnt(0) implicit) -> buf[cur] ready;
        // also guarantees all waves finished reading buf[cur^1] last iter.
        __syncthreads();
        if (it + 1 < ntiles) issue_kv(cur ^ 1, st0 + it + 1);

        // S^T = K Q^T (A = K-frag, B = Q-frag), 2 s-tiles of 32
        f32x16 st[2];
#pragma unroll
        for (int nt = 0; nt < 2; nt++)
#pragma unroll
            for (int r = 0; r < 16; r++) st[nt][r] = 0.f;
        __builtin_amdgcn_s_setprio(1);
#pragma unroll
        for (int kc = 0; kc < 8; kc++)
#pragma unroll
            for (int nt = 0; nt < 2; nt++) {
                int row = nt * 32 + q31;
                bf16x8 kf = *(const bf16x8*)&K_lds[cur][row * 128 + (((kc * 2 + hi) ^ (row & 7)) * 8)];
                st[nt] = __builtin_amdgcn_mfma_f32_32x32x16_bf16(kf, qf[kc], st[nt], 0, 0, 0);
            }
        __builtin_amdgcn_s_setprio(0);

        // causal mask on diagonal-region tiles (wave-uniform branch)
        if (st0 + it >= 2 * jt) {
            int qg = q0 + wave * 32 + q31;
#pragma unroll
            for (int nt = 0; nt < 2; nt++)
#pragma unroll
                for (int r = 0; r < 16; r++) {
                    int sg = s0 + nt * 32 + (r & 3) + 8 * (r >> 2) + 4 * hi;
                    if (sg > qg) st[nt][r] = -INFINITY;
                }
        }

        // p = exp2(s - M0); accumulate denominator per-lane (one q per lane)
#pragma unroll
        for (int nt = 0; nt < 2; nt++)
#pragma unroll
            for (int r = 0; r < 16; r++) {
                st[nt][r] = exp2f(st[nt][r] - M0);
                lsum += st[nt][r];
            }

        // build PV A-frags in-register: 16 cvt_pk + 8 permlane32_swap.
        // pa[sb] reg j at lane(q,hi) = P[q][sb*16 + hi*8 + 2j, +2j+1]
        bf16x8 pa[4];
#pragma unroll
        for (int nt = 0; nt < 2; nt++) {
            uint32_t x0 = cvtpk(st[nt][0],  st[nt][1]);
            uint32_t x1 = cvtpk(st[nt][2],  st[nt][3]);
            uint32_t y0 = cvtpk(st[nt][4],  st[nt][5]);
            uint32_t y1 = cvtpk(st[nt][6],  st[nt][7]);
            pl32swap(x0, y0);   // x0=[(s0,s1)|(s8,s9)]  y0=[(s4,s5)|(s12,s13)]
            pl32swap(x1, y1);   // x1=[(s2,s3)|(s10,s11)] y1=[(s6,s7)|(s14,s15)]
            u32x4 w0 = (u32x4){x0, x1, y0, y1};
            pa[2 * nt] = *(bf16x8*)&w0;
            uint32_t z0 = cvtpk(st[nt][8],  st[nt][9]);
            uint32_t z1 = cvtpk(st[nt][10], st[nt][11]);
            uint32_t t0 = cvtpk(st[nt][12], st[nt][13]);
            uint32_t t1 = cvtpk(st[nt][14], st[nt][15]);
            pl32swap(z0, t0);
            pl32swap(z1, t1);
            u32x4 w1 = (u32x4){z0, z1, t0, t1};
            pa[2 * nt + 1] = *(bf16x8*)&w1;
        }

        // O += P V : A = pa[sb] (q x 16s), B = V-frag from vT layout [d][s]
        __builtin_amdgcn_s_setprio(1);
#pragma unroll
        for (int sb = 0; sb < 4; sb++)
#pragma unroll
            for (int ntd = 0; ntd < 4; ntd++) {
                int row = ntd * 32 + q31;
                bf16x8 vf = *(const bf16x8*)&V_lds[cur][row * 64 + (((sb * 2 + hi) ^ (row & 7)) * 8)];
                o[ntd] = __builtin_amdgcn_mfma_f32_32x32x16_bf16(pa[sb], vf, o[ntd], 0, 0, 0);
            }
        __builtin_amdgcn_s_setprio(0);
        cur ^= 1;
    }

    // each q's denominator is split across lane and lane^32
    lsum += __shfl_xor(lsum, 32, 64);

    // write unnormalized partial (bf16) + l at the LOGICAL index.
    // O tile: col=lane&31 = d (within ntd*32), row = (r&3)+8*(r>>2)+4*hi = q
    uint16_t* pp = part + (size_t)lidx * (128 * 128);
#pragma unroll
    for (int ntd = 0; ntd < 4; ntd++)
#pragma unroll
        for (int r = 0; r < 16; r++) {
            int lrow = wave * 32 + (r & 3) + 8 * (r >> 2) + 4 * hi;
            pp[lrow * 128 + ntd * 32 + q31] = bfru(o[ntd][r]);
        }
    if (lane < 32)
        ml[(size_t)lidx * 128 + wave * 32 + q31] = lsum;
}

// ---------------------------------------------------------------------------
// Kernel 4: combine split-K partials: plain sums (fixed M0 cancels).
// Grid = (batch, jt128, col-half): 256 blocks; thread = (row, col-quarter).
// ---------------------------------------------------------------------------
__global__ __launch_bounds__(256) void combine(const uint16_t* __restrict__ part,
                                               const float* __restrict__ ml,
                                               float* __restrict__ out) {
    int bidx  = blockIdx.x;
    int half  = bidx & 1;
    int jt    = (bidx >> 1) & 31;
    int batch = bidx >> 6;
    int a     = jt >> 2;
    int base  = batch * NCHUNK_PB + 2 * a * (a + 1) + (jt - 4 * a) * (a + 1);
    int nch   = a + 1;

    int tid  = threadIdx.x;
    int lrow = tid >> 1;                 // 0..127
    int c0   = half * 64 + (tid & 1) * 32;

    float Lsum = 0.f;
    f32x4 acc[8];
#pragma unroll
    for (int i = 0; i < 8; i++) acc[i] = (f32x4){0.f, 0.f, 0.f, 0.f};

    for (int c = 0; c < nch; c++) {
        Lsum += ml[(size_t)(base + c) * 128 + lrow];
        const uint16_t* p = part + (size_t)(base + c) * (128 * 128) + lrow * 128 + c0;
#pragma unroll
        for (int i = 0; i < 4; i++) {
            us8 v = *(const us8*)(p + i * 8);
#pragma unroll
            for (int j = 0; j < 8; j++)
                acc[i * 2 + (j >> 2)][j & 3] += bf2f(v[j]);
        }
    }
    float inv = 1.f / Lsum;
    size_t row = (size_t)(batch * T_ + jt * 128 + lrow);
#pragma unroll
    for (int i = 0; i < 8; i++)
        *(f32x4*)(out + row * 128 + c0 + i * 4) = acc[i] * inv;
}

// ---------------------------------------------------------------------------
extern "C" void kernel_launch(void* const* d_in, const int* in_sizes, int n_in,
                              void* d_out, int out_size, void* d_ws, size_t ws_size,
                              hipStream_t stream) {
    const float* x  = (const float*)d_in[0];
    const float* Wq = (const float*)d_in[1];
    const float* Wk = (const float*)d_in[2];
    const float* Wv = (const float*)d_in[3];
    float* out = (float*)d_out;

    uint16_t* ws = (uint16_t*)d_ws;
    uint16_t* qb = ws;                                   // 16384*128 bf16
    uint16_t* kb = qb + (size_t)16384 * 128;
    uint16_t* vT = kb + (size_t)16384 * 128;
    uint16_t* WT = vT + (size_t)16384 * 128;             // 3*128*1024
    uint16_t* part = WT + (size_t)3 * D_ * C_;           // 576*128*128 bf16
    float* ml = (float*)(part + (size_t)4 * NCHUNK_PB * 128 * 128);  // 576*128 fp32

    prep_w<<<dim3((3 * D_ * C_ + 255) / 256), dim3(256), 0, stream>>>(Wq, Wk, Wv, WT);
    qkv_gemm<<<dim3(3 * (16384 / 64)), dim3(256), 0, stream>>>(x, WT, qb, kb, vT);
    attn<<<dim3(B_ * NCHUNK_PB), dim3(256), 0, stream>>>(qb, kb, vT, part, ml);
    combine<<<dim3(B_ * 32 * 2), dim3(256), 0, stream>>>(part, ml, out);
}